// Round 10
// baseline (171.737 us; speedup 1.0000x reference)
//
#include <hip/hip_runtime.h>

#define S_LEN 2048
#define NBH 32

typedef unsigned short u16;
typedef unsigned int u32;
typedef __attribute__((ext_vector_type(8))) short bf16x8;
typedef __attribute__((ext_vector_type(16))) float f32x16;
typedef __attribute__((ext_vector_type(2))) u32 u32x2;
typedef __attribute__((ext_vector_type(4))) u32 u32x4;

#define MFMA32(A, B, C) __builtin_amdgcn_mfma_f32_32x32x16_bf16(A, B, C, 0, 0, 0)

__device__ __forceinline__ u16 f2bf(float f) {
  u32 u = __builtin_bit_cast(u32, f);
  u += 0x7fffu + ((u >> 16) & 1u);
  return (u16)(u >> 16);
}
__device__ __forceinline__ float bf2f(u16 b) {
  u32 u = ((u32)b) << 16;
  return __builtin_bit_cast(float, u);
}
__device__ __forceinline__ u32 pack2(float a, float b) {
  return (u32)f2bf(a) | ((u32)f2bf(b) << 16);
}
__device__ __forceinline__ u32 cvtpk(float a, float b) {
  u32 r;
  asm("v_cvt_pk_bf16_f32 %0, %1, %2" : "=v"(r) : "v"(a), "v"(b));
  return r;
}
__device__ __forceinline__ void gld16(const void* g, void* l) {
  __builtin_amdgcn_global_load_lds(
      (const __attribute__((address_space(1))) void*)g,
      (__attribute__((address_space(3))) void*)l, 16, 0, 0);
}

// Pack 16 f32 in 32x32 D-layout (row e=(r&3)+8*(r>>2)+4h, col=own q) into two
// B-operand bf16x8 fragments (k = ksl*16 + h*8 + j) via cvt_pk + permlane32_swap.
__device__ __forceinline__ void pack_bfrag(const f32x16& s, bf16x8& f0,
                                           bf16x8& f1) {
  u32 u0[4], u1[4];
#pragma unroll
  for (int m = 0; m < 4; ++m) {
    u0[m] = cvtpk(s[4 * m], s[4 * m + 1]);
    u1[m] = cvtpk(s[4 * m + 2], s[4 * m + 3]);
  }
  u32x2 a0 = __builtin_amdgcn_permlane32_swap(u0[0], u0[1], false, false);
  u32x2 a1 = __builtin_amdgcn_permlane32_swap(u1[0], u1[1], false, false);
  u32x2 a2 = __builtin_amdgcn_permlane32_swap(u0[2], u0[3], false, false);
  u32x2 a3 = __builtin_amdgcn_permlane32_swap(u1[2], u1[3], false, false);
  f0 = __builtin_bit_cast(bf16x8, (u32x4){a0.x, a1.x, a0.y, a1.y});
  f1 = __builtin_bit_cast(bf16x8, (u32x4){a2.x, a3.x, a2.y, a3.y});
}

// ---------- prep: K -> bf16 hi/lo blobs, V -> V^T blobs (pre-swizzled) ------
__global__ __launch_bounds__(256) void prep_kernel(
    const float* __restrict__ Hk, const float* __restrict__ Hv,
    u16* __restrict__ Khb, u16* __restrict__ Klb, u16* __restrict__ Vtb) {
  __shared__ u16 sT[64 * 66];
  const int bh = blockIdx.y, t = blockIdx.x, tid = threadIdx.x;
  const size_t base = ((size_t)bh * S_LEN + t * 64) * 64;
  const size_t bb = ((size_t)bh * 32 + t) * 4096;

#pragma unroll
  for (int i = 0; i < 2; ++i) {
    int c = tid + 256 * i;
    int row = c >> 3, ci = c & 7;
    const float* ks = Hk + base + (size_t)row * 64 + ci * 8;
    float4 a = *(const float4*)ks, b = *(const float4*)(ks + 4);
    float xs[8] = {a.x, a.y, a.z, a.w, b.x, b.y, b.z, b.w};
    u16 hi[8], lo[8];
#pragma unroll
    for (int j = 0; j < 8; ++j) {
      hi[j] = f2bf(xs[j]);
      lo[j] = f2bf(xs[j] - bf2f(hi[j]));
    }
    int o = (c & ~7) | (ci ^ (row & 7));
    *(uint4*)(Khb + bb + o * 8) = *(uint4*)hi;
    *(uint4*)(Klb + bb + o * 8) = *(uint4*)lo;

    const float* vs = Hv + base + (size_t)row * 64 + ci * 8;
    float4 va = *(const float4*)vs, vb = *(const float4*)(vs + 4);
    u16* dst = sT + row * 66 + ci * 8;
    *(u32*)(dst + 0) = pack2(va.x, va.y);
    *(u32*)(dst + 2) = pack2(va.z, va.w);
    *(u32*)(dst + 4) = pack2(vb.x, vb.y);
    *(u32*)(dst + 6) = pack2(vb.z, vb.w);
  }
  __syncthreads();

#pragma unroll
  for (int i = 0; i < 2; ++i) {
    int o = tid + 256 * i;
    int d = o >> 3, s8 = ((o & 7) ^ (d & 7)) * 8;
    u16 tmp[8];
#pragma unroll
    for (int j = 0; j < 8; ++j) tmp[j] = sT[(s8 + j) * 66 + d];
    *(uint4*)(Vtb + bb + o * 8) = *(uint4*)tmp;
  }
}

__device__ __forceinline__ void stage_pair(char* smem, int bh, int p, int tid,
                                           int wave, const u16* Khb,
                                           const u16* Klb, const u16* Vtb) {
#pragma unroll
  for (int ts = 0; ts < 2; ++ts) {
    const int tt = 2 * p + ts;
    const size_t gb = (((size_t)bh * 32 + tt) * 512 + tid) * 16;
    char* lb = smem + ts * 24576 + wave * 1024;  // wave-uniform dest
    gld16((const char*)Khb + gb, lb);
    gld16((const char*)Klb + gb, lb + 8192);
    gld16((const char*)Vtb + gb, lb + 16384);
  }
}

// ---------- fused: Q-projection prologue + causal flash attention -----------
// 8 waves; wave-sets {0-3}/{4-7} own 32 q-rows each and split even/odd KV
// tiles (merged at end). 32x32x16 MFMAs, swapped operands: lane-pair owns one
// q-column. P and Q' routed fully in-register (cvt_pk + permlane32_swap).
// LDS 48 KB: pair-buffer[2] x { Khi 8K | Klo 8K | Vt 8K }, sA aliased.
__global__ __launch_bounds__(512, 4) void attn_kernel(
    const float* __restrict__ Hin, const float* __restrict__ avAp,
    const u16* __restrict__ Khb, const u16* __restrict__ Klb,
    const u16* __restrict__ Vtb, float* __restrict__ Out) {
  __shared__ __align__(16) char smem[49152];

  const int bh = blockIdx.y;
  const int h16 = bh & 15;
  const int x = blockIdx.x;
  const int qtile = ((bh >> 4) & 1) ? x : (15 - x);  // complement pairing
  const int q0 = qtile * 128;
  const int tid = threadIdx.x, wave = tid >> 6, lane = tid & 63;
  const int ql = lane & 31;    // owned q column
  const int hh = lane >> 5;    // lane half
  const int wq = wave & 3;     // q-group (32 rows each)
  const int kset = wave >> 2;  // 0: even kv tiles, 1: odd
  const int qrow = q0 + wq * 32 + ql;
  const int npair = qtile + 1;

  // ---- prologue: stage avAp[h] fp32 linear into [0,16K) ----
  float* sAf = (float*)smem;
#pragma unroll
  for (int i = 0; i < 2; ++i) {
    int c = tid + 512 * i;
    *(float4*)(sAf + c * 4) =
        *(const float4*)(avAp + (size_t)h16 * 4096 + c * 4);
  }

  // Hin^T B-fragments (split bf16): k = ks*16 + hh*8 + j, col q = own
  bf16x8 bhin_hi[4], bhin_lo[4];
#pragma unroll
  for (int ks = 0; ks < 4; ++ks) {
    const float* src =
        Hin + ((size_t)bh * S_LEN + qrow) * 64 + ks * 16 + hh * 8;
    float4 u = *(const float4*)src;
    float4 w = *(const float4*)(src + 4);
    float xs[8] = {u.x, u.y, u.z, u.w, w.x, w.y, w.z, w.w};
#pragma unroll
    for (int j = 0; j < 8; ++j) {
      u16 t = f2bf(xs[j]);
      bhin_hi[ks][j] = (short)t;
      bhin_lo[ks][j] = (short)f2bf(xs[j] - bf2f(t));
    }
  }
  __syncthreads();

  // Q'^T = avAp^T @ Hin^T (swapped, split; 24 MFMAs): D rows = feature e
  f32x16 qacc[2];
  qacc[0] = (f32x16)0.0f;
  qacc[1] = (f32x16)0.0f;
#pragma unroll
  for (int ks = 0; ks < 4; ++ks) {
#pragma unroll
    for (int nb = 0; nb < 2; ++nb) {
      bf16x8 ahi, alo;
#pragma unroll
      for (int j = 0; j < 8; ++j) {
        float v = sAf[(ks * 16 + hh * 8 + j) * 64 + nb * 32 + ql];
        u16 t = f2bf(v);
        ahi[j] = (short)t;
        alo[j] = (short)f2bf(v - bf2f(t));
      }
      qacc[nb] = MFMA32(ahi, bhin_hi[ks], qacc[nb]);
      qacc[nb] = MFMA32(alo, bhin_hi[ks], qacc[nb]);
      qacc[nb] = MFMA32(ahi, bhin_lo[ks], qacc[nb]);
    }
  }
  __syncthreads();  // all waves done reading sA

  // issue pair-0 staging now; routing below hides the latency
  stage_pair(smem, bh, 0, tid, wave, Khb, Klb, Vtb);

  // ---- scale + split + route Q' to B-fragments, in-register ----
  const float QSCALE = 0.125f * 1.44269504088896f;  // 1/sqrt(64) * 1/ln2
  bf16x8 qhi[4], qlo[4];
#pragma unroll
  for (int nb = 0; nb < 2; ++nb) {
    f32x16 s, lo;
#pragma unroll
    for (int r = 0; r < 16; ++r) {
      float v = qacc[nb][r] * QSCALE;
      s[r] = v;
      lo[r] = v - bf2f(f2bf(v));
    }
    pack_bfrag(s, qhi[nb * 2], qhi[nb * 2 + 1]);
    pack_bfrag(lo, qlo[nb * 2], qlo[nb * 2 + 1]);
  }

  f32x16 Oacc[2];
  Oacc[0] = (f32x16)0.0f;
  Oacc[1] = (f32x16)0.0f;
  float m_r = -3.0e38f, l_r = 0.f;

  __syncthreads();  // pair-0 staged

  // ---- main loop: each wave-set consumes its parity's tile ----
  for (int p = 0; p < npair; ++p) {
    const int t = 2 * p + kset;
    const int kv0 = t * 64;
    const char* base = smem + kset * 24576;

    if (kv0 <= q0 + wq * 32 + 31) {  // wave-uniform causal activity
      // QK^T swapped (split, 24 MFMA): D[kv_local][q]
      f32x16 sacc[2];
      sacc[0] = (f32x16)0.0f;
      sacc[1] = (f32x16)0.0f;
#pragma unroll
      for (int nb = 0; nb < 2; ++nb) {
        const int krow = nb * 32 + ql;
        const int swz = (krow & 7) << 4;
#pragma unroll
        for (int ks = 0; ks < 4; ++ks) {
          const int off = krow * 128 + (((ks * 2 + hh) * 16) ^ swz);
          bf16x8 kh = *(const bf16x8*)(base + off);
          bf16x8 kl = *(const bf16x8*)(base + 8192 + off);
          sacc[nb] = MFMA32(kh, qhi[ks], sacc[nb]);
          sacc[nb] = MFMA32(kl, qhi[ks], sacc[nb]);
          sacc[nb] = MFMA32(kh, qlo[ks], sacc[nb]);
        }
      }

      // causal mask (diagonal-adjacent tiles only)
      if (kv0 + 63 > q0 + wq * 32) {
#pragma unroll
        for (int nb = 0; nb < 2; ++nb)
#pragma unroll
          for (int r = 0; r < 16; ++r) {
            int kv = kv0 + nb * 32 + (r & 3) + 8 * (r >> 2) + 4 * hh;
            if (kv > qrow) sacc[nb][r] = -1.0e30f;
          }
      }

      // online softmax (log2 domain), tree reduce + 1 partner shuffle
      float a[16];
#pragma unroll
      for (int i = 0; i < 16; ++i) a[i] = fmaxf(sacc[0][i], sacc[1][i]);
#pragma unroll
      for (int i = 0; i < 8; ++i) a[i] = fmaxf(a[i], a[i + 8]);
#pragma unroll
      for (int i = 0; i < 4; ++i) a[i] = fmaxf(a[i], a[i + 4]);
      float tmax = fmaxf(fmaxf(a[0], a[1]), fmaxf(a[2], a[3]));
      tmax = fmaxf(tmax, __shfl_xor(tmax, 32));
      if (!__all(tmax <= m_r + 8.0f)) {  // defer-max (T13)
        float mn = fmaxf(m_r, tmax);
        float corr = exp2f(m_r - mn);
        m_r = mn;
        l_r *= corr;
#pragma unroll
        for (int db = 0; db < 2; ++db)
#pragma unroll
          for (int r = 0; r < 16; ++r) Oacc[db][r] *= corr;
      }
#pragma unroll
      for (int nb = 0; nb < 2; ++nb)
#pragma unroll
        for (int r = 0; r < 16; ++r) sacc[nb][r] = exp2f(sacc[nb][r] - m_r);
#pragma unroll
      for (int i = 0; i < 16; ++i) a[i] = sacc[0][i] + sacc[1][i];
#pragma unroll
      for (int i = 0; i < 8; ++i) a[i] += a[i + 8];
#pragma unroll
      for (int i = 0; i < 4; ++i) a[i] += a[i + 4];
      float rs = (a[0] + a[1]) + (a[2] + a[3]);
      rs += __shfl_xor(rs, 32);
      l_r += rs;

      // P -> B-fragments fully in-register
      bf16x8 pa[4];
      pack_bfrag(sacc[0], pa[0], pa[1]);
      pack_bfrag(sacc[1], pa[2], pa[3]);

      // PV swapped (8 MFMA): D rows = d, col = q
#pragma unroll
      for (int db = 0; db < 2; ++db) {
        const int vrow = db * 32 + ql;
        const int swz = (vrow & 7) << 4;
#pragma unroll
        for (int ks = 0; ks < 4; ++ks) {
          const int off = vrow * 128 + (((ks * 2 + hh) * 16) ^ swz);
          bf16x8 vb = *(const bf16x8*)(base + 16384 + off);
          Oacc[db] = MFMA32(vb, pa[ks], Oacc[db]);
        }
      }
    }

    __syncthreads();  // all waves done reading pair p
    if (p + 1 < npair) stage_pair(smem, bh, p + 1, tid, wave, Khb, Klb, Vtb);
    __syncthreads();  // staged (vmcnt drained before barrier)
  }

  // ---- merge odd-set state into even-set via LDS; epilogue by set 0 ----
  const int idx = wq * 64 + lane;  // 0..255, matches partner wave
  if (kset == 1) {
#pragma unroll
    for (int db = 0; db < 2; ++db)
#pragma unroll
      for (int m4 = 0; m4 < 4; ++m4) {
        float4 v = make_float4(Oacc[db][4 * m4], Oacc[db][4 * m4 + 1],
                               Oacc[db][4 * m4 + 2], Oacc[db][4 * m4 + 3]);
        *(float4*)(smem + idx * 144 + db * 64 + m4 * 16) = v;
      }
    *(float*)(smem + 36864 + idx * 8) = m_r;
    *(float*)(smem + 36864 + idx * 8 + 4) = l_r;
  }
  __syncthreads();
  if (kset == 0) {
    float mp = *(const float*)(smem + 36864 + idx * 8);
    float lp = *(const float*)(smem + 36864 + idx * 8 + 4);
    float mo = fmaxf(m_r, mp);
    float ca = exp2f(m_r - mo), cb = exp2f(mp - mo);
    float linv = 1.0f / (l_r * ca + lp * cb);
    float* orow = Out + ((size_t)bh * S_LEN + qrow) * 64;
#pragma unroll
    for (int db = 0; db < 2; ++db)
#pragma unroll
      for (int m4 = 0; m4 < 4; ++m4) {
        float4 vp = *(const float4*)(smem + idx * 144 + db * 64 + m4 * 16);
        float4 o;
        o.x = (Oacc[db][4 * m4 + 0] * ca + vp.x * cb) * linv;
        o.y = (Oacc[db][4 * m4 + 1] * ca + vp.y * cb) * linv;
        o.z = (Oacc[db][4 * m4 + 2] * ca + vp.z * cb) * linv;
        o.w = (Oacc[db][4 * m4 + 3] * ca + vp.w * cb) * linv;
        *(float4*)(orow + db * 32 + m4 * 8 + hh * 4) = o;
      }
  }
}

extern "C" void kernel_launch(void* const* d_in, const int* in_sizes, int n_in,
                              void* d_out, int out_size, void* d_ws,
                              size_t ws_size, hipStream_t stream) {
  const float* Hin = (const float*)d_in[0];
  const float* Hk = (const float*)d_in[1];
  const float* Hv = (const float*)d_in[2];
  // d_in[3] = mask (analytic), d_in[5] = F_hidden (=64)
  const float* avAp = (const float*)d_in[4];
  float* Out = (float*)d_out;

  const size_t N = (size_t)NBH * S_LEN * 64;
  u16* Khb = (u16*)d_ws;
  u16* Klb = Khb + N;
  u16* Vtb = Klb + N;

  prep_kernel<<<dim3(S_LEN / 64, NBH), dim3(256), 0, stream>>>(Hk, Hv, Khb,
                                                               Klb, Vtb);
  attn_kernel<<<dim3(S_LEN / 128, NBH), dim3(512), 0, stream>>>(
      Hin, avAp, Khb, Klb, Vtb, Out);
}